// Round 5
// baseline (223.852 us; speedup 1.0000x reference)
//
#include <hip/hip_runtime.h>
#include <hip/hip_bf16.h>

#define H 128
#define TILE_PTS 32
#define ROW_STRIDE 136   // f16 elems per LDS row: 128 + 8 pad (16B-aligned rows)
#define NBLK 512         // blocks for the scatter kernel
#define BT 1024
#define BSH 4            // 16 nodes per coarse bucket
#define NPB (1 << BSH)
#define CAP 2048         // rec slots per bucket (mean ~1600, sd ~40 -> +11 sigma)
#define RAWN (CAP + 32)
#define HBUF (TILE_PTS * ROW_STRIDE)   // shorts per h1 buffer

typedef __attribute__((ext_vector_type(8))) short short8;
typedef __attribute__((ext_vector_type(4))) float float4v;
typedef __attribute__((ext_vector_type(2))) float float2v;
typedef __attribute__((ext_vector_type(4))) int int4v;
typedef __attribute__((ext_vector_type(16))) float f32x16;
typedef _Float16 half8 __attribute__((ext_vector_type(8)));
typedef _Float16 half2 __attribute__((ext_vector_type(2)));

static __device__ __forceinline__ unsigned short f2bf(float f) {
    unsigned u = __float_as_uint(f);
    unsigned r = (u + 0x7fffu + ((u >> 16) & 1u)) >> 16;
    return (unsigned short)r;
}
static __device__ __forceinline__ unsigned pkbf(float a, float b) {
    __hip_bfloat162 h = __float22bfloat162_rn(float2{a, b});
    return *reinterpret_cast<unsigned*>(&h);
}
static __device__ __forceinline__ unsigned short f2h(float f) {
    _Float16 h = (_Float16)f;
    unsigned short u;
    __builtin_memcpy(&u, &h, 2);
    return u;
}
static __device__ __forceinline__ float h2f(unsigned short us) {
    _Float16 h;
    __builtin_memcpy(&h, &us, 2);
    return (float)h;
}

// ---------------------------------------------------------------------------
// K1: hist + atomic range reservation + scatter into slotted xb[nbuk][CAP].
// Order within a bucket is arbitrary. 4 pts/thread vectorized. Also W2->f16T.
// ---------------------------------------------------------------------------
__global__ __launch_bounds__(BT)
void scatter_slot(const int* __restrict__ bidx, const float* __restrict__ x,
                  const float* __restrict__ W2, unsigned short* __restrict__ W2T,
                  int* __restrict__ gcnt, uint2* __restrict__ xb,
                  int P, int nbuk) {
    extern __shared__ int lh[];   // nbuk ints: hist, then write cursors
    const int b = blockIdx.x, t = threadIdx.x;
    for (int i = b * BT + t; i < H * H; i += NBLK * BT) {
        int n = i >> 7, k = i & 127;
        W2T[i] = f2h(W2[k * H + n]);          // f16 transpose for GEMM2
    }
    for (int i = t; i < nbuk; i += BT) lh[i] = 0;
    __syncthreads();
    const int chunk4 = (((P + NBLK - 1) / NBLK) + 3) & ~3;
    const int lo = b * chunk4;
    const int hi = (lo + chunk4 < P) ? lo + chunk4 : P;
    for (int p4 = lo + 4 * t; p4 < hi; p4 += 4 * BT) {
        if (p4 + 4 <= hi) {
            int4v i4 = *(const int4v*)&bidx[p4];
            atomicAdd(&lh[i4.x >> BSH], 1);
            atomicAdd(&lh[i4.y >> BSH], 1);
            atomicAdd(&lh[i4.z >> BSH], 1);
            atomicAdd(&lh[i4.w >> BSH], 1);
        } else {
            for (int p = p4; p < hi; ++p) atomicAdd(&lh[bidx[p] >> BSH], 1);
        }
    }
    __syncthreads();
    for (int i = t; i < nbuk; i += BT) {
        int c = lh[i];
        lh[i] = (c > 0) ? atomicAdd(&gcnt[i], c) : 0;
    }
    __syncthreads();
    auto emit = [&](int idx, float x0, float x1, float x2) {
        int pos = atomicAdd(&lh[idx >> BSH], 1);
        if (pos < CAP) {
            uint2 r;
            r.x = (unsigned)f2h(x0) | ((unsigned)f2h(x1) << 16);
            r.y = (unsigned)f2h(x2) | ((unsigned)(idx & (NPB - 1)) << 16);
            xb[(size_t)(idx >> BSH) * CAP + pos] = r;
        }
    };
    for (int p4 = lo + 4 * t; p4 < hi; p4 += 4 * BT) {
        if (p4 + 4 <= hi) {
            int4v i4 = *(const int4v*)&bidx[p4];
            float4v xa = *(const float4v*)(x + (size_t)p4 * 3);
            float4v xbv = *(const float4v*)(x + (size_t)p4 * 3 + 4);
            float4v xc = *(const float4v*)(x + (size_t)p4 * 3 + 8);
            emit(i4.x, xa[0], xa[1], xa[2]);
            emit(i4.y, xa[3], xbv[0], xbv[1]);
            emit(i4.z, xbv[2], xbv[3], xc[0]);
            emit(i4.w, xc[1], xc[2], xc[3]);
        } else {
            for (int p = p4; p < hi; ++p)
                emit(bidx[p], x[p * 3 + 0], x[p * 3 + 1], x[p * 3 + 2]);
        }
    }
}

// ---------------------------------------------------------------------------
// K2 v15: v13 structure/datapath (issue-bound: VALU 40% + MFMA 29% at 4
// blocks/CU) with the GEMM2 switched to mfma_f32_32x32x16_f16:
//   - 8 MFMA per 32pt x 32col tile (was 16 x 16x16x32) -> fewer issue slots
//   - single f32x16 acc; running max 8 nested fmaxf (v_max3) vs 16 v_max
//   - A-frag: row = lane&31, k = (lane>>5)*8 + kk*16  (mirrors verified
//     16x16 pattern row=lane&15, k=(lane>>4)*8)
//   - C/D: col = lane&31, row = (reg&3) + 8*(reg>>2) + 4*(lane>>5)  [m74]
//   - 1-bit XOR swizzle on the khalf address bit (col bit3 ^= (row>>3)&1)
//     on BOTH stage-store and A-read: 32-row reads at stride 136 are 4-way
//     bank conflicted; swizzle -> 2-way (free, m136).
// ---------------------------------------------------------------------------
__global__ __launch_bounds__(256, 4)
void node_kernel15(const uint2* __restrict__ xb, const int* __restrict__ gcnt,
                   const float* __restrict__ W1, const float* __restrict__ b1,
                   const float* __restrict__ gamma, const float* __restrict__ beta,
                   const float* __restrict__ rmean, const float* __restrict__ rvar,
                   const unsigned short* __restrict__ W2T, const float* __restrict__ b2,
                   float* __restrict__ out, int N)
{
    __shared__ __align__(16) unsigned short pool[2 * HBUF];  // 17408 B
    __shared__ __align__(16) uint2 srt[RAWN];                // 16640 B
    __shared__ int basec[NPB + 1];
    __shared__ int cur[NPB];

    const int bk   = blockIdx.x;
    const int t    = threadIdx.x;
    const int lane = t & 63;
    const int wave = t >> 6;
    const int g  = t & 15;
    const int q  = t >> 4;
    const int c0 = g * 8;

    // GEMM1 constants (BN folded), 8 fixed cols per thread, packed f16 pairs
    half2 w1h[3][4], b1h[4];
    #pragma unroll
    for (int jp = 0; jp < 4; ++jp) {
        #pragma unroll
        for (int e = 0; e < 2; ++e) {
            int c = c0 + 2 * jp + e;
            float sc = gamma[c] * rsqrtf(rvar[c] + 1e-5f);
            w1h[0][jp][e] = (_Float16)(W1[0 * H + c] * sc);
            w1h[1][jp][e] = (_Float16)(W1[1 * H + c] * sc);
            w1h[2][jp][e] = (_Float16)(W1[2 * H + c] * sc);
            b1h[jp][e]    = (_Float16)((b1[c] - rmean[c]) * sc + beta[c]);
        }
    }

    // W2 fragments (f16) for 32x32x16: wave owns cols [wave*32, wave*32+32)
    const int col   = lane & 31;
    const int khalf = lane >> 5;
    const int nn = wave * 32 + col;
    half8 bfrag[8];
    float b2v = b2[nn];
    #pragma unroll
    for (int kk = 0; kk < 8; ++kk)
        bfrag[kk] = *(const half8*)(const void*)&W2T[nn * H + kk * 16 + khalf * 8];

    // ---- load bucket once (global -> pool as raw recs) ----
    uint2* raw = (uint2*)pool;                       // 2176 slots >= CAP
    int n_b = gcnt[bk];
    if (n_b > CAP) n_b = CAP;
    const uint2* src = xb + (size_t)bk * CAP;
    for (int p = t; p < n_b; p += 256) raw[p] = src[p];
    if (t < NPB) cur[t] = 0;
    __syncthreads();
    // ---- hist ----
    for (int p = t; p < n_b; p += 256)
        atomicAdd(&cur[raw[p].y >> 16], 1);
    __syncthreads();
    if (t == 0) {
        int run = 0;
        #pragma unroll
        for (int i = 0; i < NPB; ++i) { int c = cur[i]; basec[i] = run; run += c; }
        basec[NPB] = run;
    }
    __syncthreads();
    if (t < NPB) cur[t] = basec[t];
    __syncthreads();
    // ---- scatter to sorted srt ----
    for (int p = t; p < n_b; p += 256) {
        uint2 r = raw[p];
        int pos = atomicAdd(&cur[r.y >> 16], 1);
        srt[pos] = r;
    }
    for (int p = n_b + t; p < n_b + TILE_PTS; p += 256)
        if (p < RAWN) srt[p] = uint2{0u, 0u};
    __syncthreads();   // raw dead; pool becomes h1 dbuf

    const f32x16 zero16 = {0.f,0.f,0.f,0.f,0.f,0.f,0.f,0.f,
                           0.f,0.f,0.f,0.f,0.f,0.f,0.f,0.f};
    const float NEG_INF = -__builtin_inff();
    const half2 zero2h = {(_Float16)0.f, (_Float16)0.f};
    const int nodebase = bk << BSH;
    const int nlocal = (N - nodebase < NPB) ? (N - nodebase) : NPB;

    // flat LDS offsets (shorts), with 1-bit khalf XOR swizzle (bit 3)
    const int swz_st = ((q >> 3) & 1) << 3;            // same for q and q+16
    const int st0 = q * ROW_STRIDE + (c0 ^ swz_st);    // stage slot, point q
    const int st1 = (q + 16) * ROW_STRIDE + (c0 ^ swz_st);  // point q+16
    // A-frag base: row = col(lane&31), khalf bit swizzled by (row>>3)&1
    const int arS = col * ROW_STRIDE + ((khalf ^ ((col >> 3) & 1)) * 8);

    // stage one point's 8 cols from rec r into buffer hs at slot offset so.
    #define STAGE_PT(r, hs, so)                                            \
    {                                                                      \
        half2 a0 = __builtin_bit_cast(half2,                               \
            __builtin_amdgcn_perm(0u, (r).x, 0x01000100u));                \
        half2 a1 = __builtin_bit_cast(half2,                               \
            __builtin_amdgcn_perm(0u, (r).x, 0x03020302u));                \
        half2 a2 = __builtin_bit_cast(half2,                               \
            __builtin_amdgcn_perm(0u, (r).y, 0x01000100u));                \
        int4v pk;                                                          \
        _Pragma("unroll")                                                  \
        for (int jp = 0; jp < 4; ++jp) {                                   \
            half2 hh = b1h[jp];                                            \
            hh = __builtin_elementwise_fma(a0, w1h[0][jp], hh);            \
            hh = __builtin_elementwise_fma(a1, w1h[1][jp], hh);            \
            hh = __builtin_elementwise_fma(a2, w1h[2][jp], hh);            \
            hh = __builtin_elementwise_max(hh, zero2h);                    \
            pk[jp] = __builtin_bit_cast(int, hh);                          \
        }                                                                  \
        *(int4v*)(void*)&(hs)[so] = pk;                                    \
    }

    for (int j = 0; j < nlocal; ++j) {
        const int startj = basec[j];
        const int n      = basec[j + 1] - startj;
        const int ntiles = (n + TILE_PTS - 1) >> 5;

        float vmx = NEG_INF;

        if (ntiles > 0) {
            unsigned short* hb = pool;          // compute buffer
            unsigned short* hs = pool + HBUF;   // stage buffer
            {
                uint2 r0 = srt[startj + q];
                uint2 r1 = srt[startj + q + 16];
                STAGE_PT(r0, hb, st0);
                STAGE_PT(r1, hb, st1);
            }
            __syncthreads();

            for (int tile = 0; tile < ntiles; ++tile) {
                const int tb = tile * TILE_PTS;
                const bool have = (tile + 1 < ntiles);

                uint2 n0, n1;
                if (have) {
                    n0 = srt[startj + tb + TILE_PTS + q];
                    n1 = srt[startj + tb + TILE_PTS + 16 + q];
                }

                // ---- 8 x mfma_32x32x16_f16 on hb; kk=0 uses zero C ----
                f32x16 acc;
                {
                    half8 a0v = *(const half8*)(const void*)&hb[arS];
                    acc = __builtin_amdgcn_mfma_f32_32x32x16_f16(a0v, bfrag[0], zero16, 0, 0, 0);
                }
                #pragma unroll
                for (int kk = 1; kk < 8; ++kk) {
                    half8 av = *(const half8*)(const void*)&hb[arS + kk * 16];
                    acc = __builtin_amdgcn_mfma_f32_32x32x16_f16(av, bfrag[kk], acc, 0, 0, 0);
                }

                // ---- stage next tile into hs (overlaps MFMA) ----
                if (have) {
                    STAGE_PT(n0, hs, st0);
                    STAGE_PT(n1, hs, st1);
                }

                // ---- running max over the 32 point-rows ----
                if (tb + TILE_PTS <= n) {
                    #pragma unroll
                    for (int i = 0; i < 8; ++i)
                        vmx = fmaxf(fmaxf(acc[2 * i], acc[2 * i + 1]), vmx);
                } else {
                    #pragma unroll
                    for (int r = 0; r < 16; ++r) {
                        const int row = (r & 3) + 8 * (r >> 2) + 4 * khalf;
                        vmx = fmaxf(vmx, (tb + row < n) ? acc[r] : NEG_INF);
                    }
                }
                __syncthreads();
                unsigned short* tmp = hb; hb = hs; hs = tmp;
            }
        }

        // ---- merge row-halves + write this wave's 32 cols ----
        vmx = fmaxf(vmx, __shfl_xor(vmx, 32, 64));
        if (lane < 32) {
            float* orow = out + (size_t)(nodebase + j) * H + wave * 32;
            orow[lane] = fmaxf(vmx + b2v, 0.f);   // relu + empty-node fill
        }
    }
    #undef STAGE_PT
}

// ---------------------------------------------------------------------------
// Tier B fallback: global-atomic counting sort + sorted node kernel (bf16)
// ---------------------------------------------------------------------------
__global__ void histB_kernel(const int* __restrict__ bidx, int* __restrict__ counts, int P) {
    int p = blockIdx.x * 256 + threadIdx.x;
    if (p < P) atomicAdd(&counts[bidx[p]], 1);
}
__global__ __launch_bounds__(1024)
void scanB_kernel(const int* __restrict__ counts, int* __restrict__ starts,
                  int* __restrict__ cursor, int N) {
    __shared__ int sums[1024];
    const int t = threadIdx.x;
    const int chunk = (N + 1023) >> 10;
    const int lo = t * chunk;
    const int hi = (lo + chunk < N) ? lo + chunk : N;
    int s = 0;
    for (int i = lo; i < hi; ++i) s += counts[i];
    sums[t] = s;
    __syncthreads();
    #pragma unroll
    for (int off = 1; off < 1024; off <<= 1) {
        int a = (t >= off) ? sums[t - off] : 0;
        __syncthreads();
        sums[t] += a;
        __syncthreads();
    }
    int run = sums[t] - s;
    for (int i = lo; i < hi; ++i) { starts[i] = run; cursor[i] = run; run += counts[i]; }
    if (t == 1023) starts[N] = sums[1023];
}
__global__ void scatterB_kernel(const int* __restrict__ bidx, const float* __restrict__ x,
                                int* __restrict__ cursor, uint2* __restrict__ xs, int P) {
    int p = blockIdx.x * 256 + threadIdx.x;
    if (p < P) {
        int pos = atomicAdd(&cursor[bidx[p]], 1);
        uint2 r;
        r.x = (unsigned)f2h(x[p * 3 + 0]) | ((unsigned)f2h(x[p * 3 + 1]) << 16);
        r.y = (unsigned)f2h(x[p * 3 + 2]);
        xs[pos] = r;
    }
}
__global__ void convw2_kernel(const float* __restrict__ W2, unsigned short* __restrict__ W2T) {
    int i = blockIdx.x * 256 + threadIdx.x;
    if (i < H * H) {
        int n = i >> 7, k = i & 127;
        W2T[i] = f2bf(W2[k * H + n]);
    }
}

__global__ __launch_bounds__(256, 4)
void node_kernelB(const uint2* __restrict__ xs,
                  const int*   __restrict__ starts,
                  const float* __restrict__ W1, const float* __restrict__ b1,
                  const float* __restrict__ gamma, const float* __restrict__ beta,
                  const float* __restrict__ rmean, const float* __restrict__ rvar,
                  const unsigned short* __restrict__ W2T, const float* __restrict__ b2,
                  float* __restrict__ out, int N)
{
    __shared__ __align__(16) unsigned short h1s[2][TILE_PTS * ROW_STRIDE];
    const int t = threadIdx.x, lane = t & 63, wave = t >> 6;
    const int g = t & 15, q = t >> 4, c0 = g * 8;
    float2v w1f2[3][4], b1f2[4];
    #pragma unroll
    for (int jp = 0; jp < 4; ++jp)
        #pragma unroll
        for (int e = 0; e < 2; ++e) {
            int c = c0 + 2 * jp + e;
            float sc = gamma[c] * rsqrtf(rvar[c] + 1e-5f);
            w1f2[0][jp][e] = W1[0 * H + c] * sc;
            w1f2[1][jp][e] = W1[1 * H + c] * sc;
            w1f2[2][jp][e] = W1[2 * H + c] * sc;
            b1f2[jp][e]    = (b1[c] - rmean[c]) * sc + beta[c];
        }
    const int bn = lane & 15, kq = (lane >> 4) * 8;
    short8 bfrag[2][4]; float b2v[2];
    #pragma unroll
    for (int nt = 0; nt < 2; ++nt) {
        const int nn = wave * 32 + nt * 16 + bn;
        b2v[nt] = b2[nn];
        #pragma unroll
        for (int kk = 0; kk < 4; ++kk)
            bfrag[nt][kk] = *(const short8*)&W2T[nn * H + kk * 32 + kq];
    }
    const float4v zero4 = {0.f, 0.f, 0.f, 0.f};
    const float NEG_INF = -__builtin_inff();
    const float2v zero2 = {0.f, 0.f};
    for (int node = blockIdx.x; node < N; node += gridDim.x) {
        const int start = starts[node];
        const int n = starts[node + 1] - start;
        const int ntiles = (n + TILE_PTS - 1) >> 5;
        float2v vmax2[2];
        vmax2[0] = float2v{NEG_INF, NEG_INF};
        vmax2[1] = float2v{NEG_INF, NEG_INF};
        auto loadx = [&](int tb, float xv[2][3]) {
            #pragma unroll
            for (int i = 0; i < 2; ++i) {
                uint2 r = xs[start + tb + q + 16 * i];
                xv[i][0] = h2f((unsigned short)(r.x & 0xffffu));
                xv[i][1] = h2f((unsigned short)(r.x >> 16));
                xv[i][2] = h2f((unsigned short)(r.y & 0xffffu));
            }
        };
        auto stage = [&](const float xv[2][3], unsigned short* buf) {
            #pragma unroll
            for (int i = 0; i < 2; ++i) {
                const int pl = q + 16 * i;
                float2v a0 = {xv[i][0], xv[i][0]};
                float2v a1 = {xv[i][1], xv[i][1]};
                float2v a2 = {xv[i][2], xv[i][2]};
                int4v pk;
                #pragma unroll
                for (int jp = 0; jp < 4; ++jp) {
                    float2v h = b1f2[jp];
                    h = __builtin_elementwise_fma(a0, w1f2[0][jp], h);
                    h = __builtin_elementwise_fma(a1, w1f2[1][jp], h);
                    h = __builtin_elementwise_fma(a2, w1f2[2][jp], h);
                    h = __builtin_elementwise_max(h, zero2);
                    pk[jp] = (int)pkbf(h[0], h[1]);
                }
                *(int4v*)(void*)&buf[pl * ROW_STRIDE + c0] = pk;
            }
        };
        if (ntiles > 0) {
            float xv[2][3];
            loadx(0, xv);
            stage(xv, h1s[0]);
            __syncthreads();
            int pb = 0;
            for (int tile = 0; tile < ntiles; ++tile) {
                const int tb = tile * TILE_PTS;
                const bool havenext = (tile + 1 < ntiles);
                float nx[2][3];
                if (havenext) loadx(tb + TILE_PTS, nx);
                float4v acc[2][2];
                const unsigned short* hb = h1s[pb];
                {
                    short8 a0 = *(const short8*)&hb[bn * ROW_STRIDE + kq];
                    short8 a1 = *(const short8*)&hb[(16 + bn) * ROW_STRIDE + kq];
                    #pragma unroll
                    for (int nt = 0; nt < 2; ++nt) {
                        acc[0][nt] = __builtin_amdgcn_mfma_f32_16x16x32_bf16(a0, bfrag[nt][0], zero4, 0, 0, 0);
                        acc[1][nt] = __builtin_amdgcn_mfma_f32_16x16x32_bf16(a1, bfrag[nt][0], zero4, 0, 0, 0);
                    }
                }
                #pragma unroll
                for (int kk = 1; kk < 4; ++kk) {
                    short8 a0 = *(const short8*)&hb[bn * ROW_STRIDE + kk * 32 + kq];
                    short8 a1 = *(const short8*)&hb[(16 + bn) * ROW_STRIDE + kk * 32 + kq];
                    #pragma unroll
                    for (int nt = 0; nt < 2; ++nt) {
                        acc[0][nt] = __builtin_amdgcn_mfma_f32_16x16x32_bf16(a0, bfrag[nt][kk], acc[0][nt], 0, 0, 0);
                        acc[1][nt] = __builtin_amdgcn_mfma_f32_16x16x32_bf16(a1, bfrag[nt][kk], acc[1][nt], 0, 0, 0);
                    }
                }
                if (havenext) stage(nx, h1s[pb ^ 1]);
                if (tb + TILE_PTS <= n) {
                    #pragma unroll
                    for (int ps = 0; ps < 2; ++ps)
                        #pragma unroll
                        for (int nt = 0; nt < 2; ++nt) {
                            vmax2[nt] = __builtin_elementwise_max(vmax2[nt],
                                          float2v{acc[ps][nt][0], acc[ps][nt][1]});
                            vmax2[nt] = __builtin_elementwise_max(vmax2[nt],
                                          float2v{acc[ps][nt][2], acc[ps][nt][3]});
                        }
                } else {
                    #pragma unroll
                    for (int ps = 0; ps < 2; ++ps)
                        #pragma unroll
                        for (int r = 0; r < 4; ++r) {
                            const int pl = ps * 16 + (lane >> 4) * 4 + r;
                            const bool valid = (tb + pl) < n;
                            vmax2[0][r & 1] = fmaxf(vmax2[0][r & 1], valid ? acc[ps][0][r] : NEG_INF);
                            vmax2[1][r & 1] = fmaxf(vmax2[1][r & 1], valid ? acc[ps][1][r] : NEG_INF);
                        }
                }
                __syncthreads();
                pb ^= 1;
            }
        }
        float vmax0 = fmaxf(vmax2[0][0], vmax2[0][1]);
        float vmax1 = fmaxf(vmax2[1][0], vmax2[1][1]);
        vmax0 = fmaxf(vmax0, __shfl_xor(vmax0, 16, 64));
        vmax0 = fmaxf(vmax0, __shfl_xor(vmax0, 32, 64));
        vmax1 = fmaxf(vmax1, __shfl_xor(vmax1, 16, 64));
        vmax1 = fmaxf(vmax1, __shfl_xor(vmax1, 32, 64));
        if (lane < 16) {
            float* orow = out + (size_t)node * H + wave * 32;
            orow[lane]      = fmaxf(vmax0 + b2v[0], 0.f);
            orow[16 + lane] = fmaxf(vmax1 + b2v[1], 0.f);
        }
    }
}

extern "C" void kernel_launch(void* const* d_in, const int* in_sizes, int n_in,
                              void* d_out, int out_size, void* d_ws, size_t ws_size,
                              hipStream_t stream) {
    const float* x     = (const float*)d_in[0];
    const int*   bidx  = (const int*)  d_in[1];
    const float* W1    = (const float*)d_in[3];
    const float* b1    = (const float*)d_in[4];
    const float* gamma = (const float*)d_in[5];
    const float* beta  = (const float*)d_in[6];
    const float* rmean = (const float*)d_in[7];
    const float* rvar  = (const float*)d_in[8];
    const float* W2    = (const float*)d_in[9];
    const float* b2    = (const float*)d_in[10];
    float* out = (float*)d_out;

    const int P = in_sizes[1];
    const int N = out_size / H;
    const int nbuk = (N + NPB - 1) >> BSH;

    // Tier A layout: W2T | gcnt | xb[nbuk][CAP]
    const size_t szW2T = 32768;
    const size_t szG   = (size_t)4 * ((nbuk + 63) & ~63);
    const size_t szXb  = (size_t)8 * ((size_t)CAP * nbuk + 64);
    const size_t needA = szW2T + szG + szXb + 256;
    const size_t lds1  = (size_t)4 * nbuk;

    char* w = (char*)d_ws;

    if (lds1 <= 60000 && ws_size >= needA) {
        unsigned short* W2T = (unsigned short*)w;
        int* gcnt = (int*)(w + szW2T);
        uint2* xb = (uint2*)(w + szW2T + szG);

        hipMemsetAsync(gcnt, 0, (size_t)nbuk * sizeof(int), stream);
        scatter_slot<<<NBLK, BT, lds1, stream>>>(bidx, x, W2, W2T, gcnt, xb, P, nbuk);
        node_kernel15<<<nbuk, 256, 0, stream>>>(xb, gcnt, W1, b1, gamma, beta,
                                                rmean, rvar, W2T, b2, out, N);
        return;
    }

    // Tier B: global-atomic counting sort
    const int Npad = (N + 63) & ~63;
    const size_t szStarts = (size_t)4 * (Npad + 64);
    const size_t szCnt    = (size_t)4 * Npad;
    const size_t szRec    = (size_t)8 * (P + 64);
    const size_t needB    = szStarts + szW2T + 2 * szCnt + szRec + 256;
    if (ws_size >= needB) {
        int* starts = (int*)w;
        unsigned short* W2T = (unsigned short*)(w + szStarts);
        int* counts = (int*)(w + szStarts + szW2T);
        int* cursor = (int*)(w + szStarts + szW2T + szCnt);
        uint2* xs   = (uint2*)(w + szStarts + szW2T + 2 * szCnt);

        hipMemsetAsync(counts, 0, (size_t)N * sizeof(int), stream);
        const int pblocks = (P + 255) / 256;
        const int grid = (N < 2048) ? N : 2048;
        convw2_kernel<<<(H * H + 255) / 256, 256, 0, stream>>>(W2, W2T);
        histB_kernel<<<pblocks, 256, 0, stream>>>(bidx, counts, P);
        scanB_kernel<<<1, 1024, 0, stream>>>(counts, starts, cursor, N);
        scatterB_kernel<<<pblocks, 256, 0, stream>>>(bidx, x, cursor, xs, P);
        node_kernelB<<<grid, 256, 0, stream>>>(xs, starts, W1, b1, gamma, beta,
                                               rmean, rvar, W2T, b2, out, N);
    }
}

// Round 6
// 217.191 us; speedup vs baseline: 1.0307x; 1.0307x over previous
//
#include <hip/hip_runtime.h>
#include <hip/hip_bf16.h>

#define H 128
#define TILE64 64
#define ROW_STRIDE 136   // f16 elems per LDS row: 128 + 8 pad (16B-aligned rows)
#define NBLK 512         // blocks for the scatter kernel
#define BT 1024
#define BSH 4            // 16 nodes per coarse bucket
#define NPB (1 << BSH)
#define CAP 2048         // rec slots per bucket ceiling (mean ~1600)
#define RAWN (CAP + 128)
#define HBUF64 (TILE64 * ROW_STRIDE)   // shorts per h1 buffer (8704)

typedef __attribute__((ext_vector_type(8))) short short8;
typedef __attribute__((ext_vector_type(4))) float float4v;
typedef __attribute__((ext_vector_type(2))) float float2v;
typedef __attribute__((ext_vector_type(4))) int int4v;
typedef __attribute__((ext_vector_type(16))) float f32x16;
typedef _Float16 half8 __attribute__((ext_vector_type(8)));
typedef _Float16 half2 __attribute__((ext_vector_type(2)));

static __device__ __forceinline__ unsigned short f2bf(float f) {
    unsigned u = __float_as_uint(f);
    unsigned r = (u + 0x7fffu + ((u >> 16) & 1u)) >> 16;
    return (unsigned short)r;
}
static __device__ __forceinline__ unsigned pkbf(float a, float b) {
    __hip_bfloat162 h = __float22bfloat162_rn(float2{a, b});
    return *reinterpret_cast<unsigned*>(&h);
}
static __device__ __forceinline__ unsigned short f2h(float f) {
    _Float16 h = (_Float16)f;
    unsigned short u;
    __builtin_memcpy(&u, &h, 2);
    return u;
}
static __device__ __forceinline__ float h2f(unsigned short us) {
    _Float16 h;
    __builtin_memcpy(&h, &us, 2);
    return (float)h;
}

// ---------------------------------------------------------------------------
// K1: hist + atomic range reservation + scatter into slotted
// xb[nbuk][nparts][capp]. part = blockIdx & (nparts-1) ~= physical XCD:
// per-XCD write working set = nbuk*capp*8B/nparts ~ 2.6MB < 4MB L2 ->
// the scattered 8B stores coalesce in the XCD-local L2 instead of
// per-line HBM RMW. nparts==1 degenerates to the old single layout.
// ---------------------------------------------------------------------------
__global__ __launch_bounds__(BT)
void scatter_slot(const int* __restrict__ bidx, const float* __restrict__ x,
                  const float* __restrict__ W2, unsigned short* __restrict__ W2T,
                  int* __restrict__ gcnt, uint2* __restrict__ xb,
                  int P, int nbuk, int nparts, int capp) {
    extern __shared__ int lh[];   // nbuk ints: hist, then write cursors
    const int b = blockIdx.x, t = threadIdx.x;
    const int part = b & (nparts - 1);
    for (int i = b * BT + t; i < H * H; i += NBLK * BT) {
        int n = i >> 7, k = i & 127;
        W2T[i] = f2h(W2[k * H + n]);          // f16 transpose for GEMM2
    }
    for (int i = t; i < nbuk; i += BT) lh[i] = 0;
    __syncthreads();
    const int chunk4 = (((P + NBLK - 1) / NBLK) + 3) & ~3;
    const int lo = b * chunk4;
    const int hi = (lo + chunk4 < P) ? lo + chunk4 : P;
    for (int p4 = lo + 4 * t; p4 < hi; p4 += 4 * BT) {
        if (p4 + 4 <= hi) {
            int4v i4 = *(const int4v*)&bidx[p4];
            atomicAdd(&lh[i4.x >> BSH], 1);
            atomicAdd(&lh[i4.y >> BSH], 1);
            atomicAdd(&lh[i4.z >> BSH], 1);
            atomicAdd(&lh[i4.w >> BSH], 1);
        } else {
            for (int p = p4; p < hi; ++p) atomicAdd(&lh[bidx[p] >> BSH], 1);
        }
    }
    __syncthreads();
    for (int i = t; i < nbuk; i += BT) {
        int c = lh[i];
        lh[i] = (c > 0) ? atomicAdd(&gcnt[i * nparts + part], c) : 0;
    }
    __syncthreads();
    auto emit = [&](int idx, float x0, float x1, float x2) {
        int pos = atomicAdd(&lh[idx >> BSH], 1);
        if (pos < capp) {
            uint2 r;
            r.x = (unsigned)f2h(x0) | ((unsigned)f2h(x1) << 16);
            r.y = (unsigned)f2h(x2) | ((unsigned)(idx & (NPB - 1)) << 16);
            xb[((size_t)(idx >> BSH) * nparts + part) * capp + pos] = r;
        }
    };
    for (int p4 = lo + 4 * t; p4 < hi; p4 += 4 * BT) {
        if (p4 + 4 <= hi) {
            int4v i4 = *(const int4v*)&bidx[p4];
            float4v xa = *(const float4v*)(x + (size_t)p4 * 3);
            float4v xbv = *(const float4v*)(x + (size_t)p4 * 3 + 4);
            float4v xc = *(const float4v*)(x + (size_t)p4 * 3 + 8);
            emit(i4.x, xa[0], xa[1], xa[2]);
            emit(i4.y, xa[3], xbv[0], xbv[1]);
            emit(i4.z, xbv[2], xbv[3], xc[0]);
            emit(i4.w, xc[1], xc[2], xc[3]);
        } else {
            for (int p = p4; p < hi; ++p)
                emit(bidx[p], x[p * 3 + 0], x[p * 3 + 1], x[p * 3 + 2]);
        }
    }
}

// ---------------------------------------------------------------------------
// K2 v16: v13/v15 were LDS-pipe-bound (~77us of 109: every wave re-read the
// same 32x128 A-tile, 4x redundancy). TILE=64 pts per barrier period; wave
// (g=wave>>1, ch=wave&1) = point-group g x 64 cols (2 col-blocks): each
// ds_read_b128 A-frag feeds 2 MFMA -> A-read traffic halves. Per-node
// cross-group max merged via 1KB scratch overlaid on the (dead) h1 pool.
// VGPR ~140 (bfrag 64 + acc 32) -> launch_bounds(256,3) cap 170, no spill.
// LDS: pool 34816 + srt 17408 + ~200 = 52.4KB -> 3 blocks/CU.
// ---------------------------------------------------------------------------
__global__ __launch_bounds__(256, 3)
void node_kernel16(const uint2* __restrict__ xb, const int* __restrict__ gcnt,
                   const float* __restrict__ W1, const float* __restrict__ b1,
                   const float* __restrict__ gamma, const float* __restrict__ beta,
                   const float* __restrict__ rmean, const float* __restrict__ rvar,
                   const unsigned short* __restrict__ W2T, const float* __restrict__ b2,
                   float* __restrict__ out, int N, int nparts, int capp)
{
    __shared__ __align__(16) unsigned short pool[2 * HBUF64];  // 34816 B
    __shared__ __align__(16) uint2 srt[RAWN];                  // 17408 B
    __shared__ int basec[NPB + 1];
    __shared__ int cur[NPB];

    const int bk   = blockIdx.x;
    const int t    = threadIdx.x;
    const int lane = t & 63;
    const int wave = t >> 6;
    const int g8   = t & 15;       // staging col-group
    const int q    = t >> 4;       // staging point-slot (0..15)
    const int c0   = g8 * 8;
    const int grp  = wave >> 1;    // point group 0/1
    const int ch   = wave & 1;     // col half 0/1

    // GEMM1 constants (BN folded), 8 fixed cols per thread, packed f16 pairs
    half2 w1h[3][4], b1h[4];
    #pragma unroll
    for (int jp = 0; jp < 4; ++jp) {
        #pragma unroll
        for (int e = 0; e < 2; ++e) {
            int c = c0 + 2 * jp + e;
            float sc = gamma[c] * rsqrtf(rvar[c] + 1e-5f);
            w1h[0][jp][e] = (_Float16)(W1[0 * H + c] * sc);
            w1h[1][jp][e] = (_Float16)(W1[1 * H + c] * sc);
            w1h[2][jp][e] = (_Float16)(W1[2 * H + c] * sc);
            b1h[jp][e]    = (_Float16)((b1[c] - rmean[c]) * sc + beta[c]);
        }
    }

    // W2 fragments (f16) for 32x32x16: wave owns cols [ch*64, ch*64+64)
    const int col   = lane & 31;
    const int khalf = lane >> 5;
    half8 bfrag0[8], bfrag1[8];
    {
        const int nn0 = ch * 64 + col;        // col-block 0
        const int nn1 = ch * 64 + 32 + col;   // col-block 1
        #pragma unroll
        for (int kk = 0; kk < 8; ++kk) {
            bfrag0[kk] = *(const half8*)(const void*)&W2T[nn0 * H + kk * 16 + khalf * 8];
            bfrag1[kk] = *(const half8*)(const void*)&W2T[nn1 * H + kk * 16 + khalf * 8];
        }
    }
    const float b2w = b2[ch * 64 + lane];   // used by writer waves (wave<2)

    // ---- load bucket once (all parts -> pool as raw recs) ----
    uint2* raw = (uint2*)pool;               // 4352 slots >= CAP
    int n_b = 0;
    for (int p = 0; p < nparts; ++p) {
        int cp = gcnt[bk * nparts + p];
        if (cp > capp) cp = capp;
        int take = (cp < CAP - n_b) ? cp : (CAP - n_b);
        const uint2* srcp = xb + ((size_t)bk * nparts + p) * capp;
        for (int i = t; i < take; i += 256) raw[n_b + i] = srcp[i];
        n_b += take;
    }
    if (t < NPB) cur[t] = 0;
    __syncthreads();
    // ---- hist ----
    for (int p = t; p < n_b; p += 256)
        atomicAdd(&cur[raw[p].y >> 16], 1);
    __syncthreads();
    if (t == 0) {
        int run = 0;
        #pragma unroll
        for (int i = 0; i < NPB; ++i) { int c = cur[i]; basec[i] = run; run += c; }
        basec[NPB] = run;
    }
    __syncthreads();
    if (t < NPB) cur[t] = basec[t];
    __syncthreads();
    // ---- scatter to sorted srt ----
    for (int p = t; p < n_b; p += 256) {
        uint2 r = raw[p];
        int pos = atomicAdd(&cur[r.y >> 16], 1);
        srt[pos] = r;
    }
    for (int p = n_b + t; p < n_b + 128; p += 256)
        if (p < RAWN) srt[p] = uint2{0u, 0u};
    __syncthreads();   // raw dead; pool becomes h1 dbuf

    const f32x16 zero16 = {0.f,0.f,0.f,0.f,0.f,0.f,0.f,0.f,
                           0.f,0.f,0.f,0.f,0.f,0.f,0.f,0.f};
    const float NEG_INF = -__builtin_inff();
    const half2 zero2h = {(_Float16)0.f, (_Float16)0.f};
    const int nodebase = bk << BSH;
    const int nlocal = (N - nodebase < NPB) ? (N - nodebase) : NPB;

    // staging offsets (4 point-slots per thread), khalf-bit XOR swizzle
    const int swz_st = ((q >> 3) & 1) << 3;            // same parity for q+16k
    const int st0 = q * ROW_STRIDE + (c0 ^ swz_st);
    const int st1 = (q + 16) * ROW_STRIDE + (c0 ^ swz_st);
    const int st2 = (q + 32) * ROW_STRIDE + (c0 ^ swz_st);
    const int st3 = (q + 48) * ROW_STRIDE + (c0 ^ swz_st);
    // A-frag base: LDS row = grp*32 + col; swizzle parity = (col>>3)&1
    const int arS = (grp * 32 + col) * ROW_STRIDE + ((khalf ^ ((col >> 3) & 1)) * 8);

    #define STAGE_PT(r, hs, so)                                            \
    {                                                                      \
        half2 a0 = __builtin_bit_cast(half2,                               \
            __builtin_amdgcn_perm(0u, (r).x, 0x01000100u));                \
        half2 a1 = __builtin_bit_cast(half2,                               \
            __builtin_amdgcn_perm(0u, (r).x, 0x03020302u));                \
        half2 a2 = __builtin_bit_cast(half2,                               \
            __builtin_amdgcn_perm(0u, (r).y, 0x01000100u));                \
        int4v pk;                                                          \
        _Pragma("unroll")                                                  \
        for (int jp = 0; jp < 4; ++jp) {                                   \
            half2 hh = b1h[jp];                                            \
            hh = __builtin_elementwise_fma(a0, w1h[0][jp], hh);            \
            hh = __builtin_elementwise_fma(a1, w1h[1][jp], hh);            \
            hh = __builtin_elementwise_fma(a2, w1h[2][jp], hh);            \
            hh = __builtin_elementwise_max(hh, zero2h);                    \
            pk[jp] = __builtin_bit_cast(int, hh);                          \
        }                                                                  \
        *(int4v*)(void*)&(hs)[so] = pk;                                    \
    }

    for (int j = 0; j < nlocal; ++j) {
        const int startj = basec[j];
        const int n      = basec[j + 1] - startj;
        const int ntiles = (n + TILE64 - 1) >> 6;

        float vmx0 = NEG_INF, vmx1 = NEG_INF;

        if (ntiles > 0) {
            unsigned short* hb = pool;            // compute buffer
            unsigned short* hs = pool + HBUF64;   // stage buffer
            {
                uint2 r0 = srt[startj + q];
                uint2 r1 = srt[startj + q + 16];
                uint2 r2 = srt[startj + q + 32];
                uint2 r3 = srt[startj + q + 48];
                STAGE_PT(r0, hb, st0);
                STAGE_PT(r1, hb, st1);
                STAGE_PT(r2, hb, st2);
                STAGE_PT(r3, hb, st3);
            }
            __syncthreads();

            for (int tile = 0; tile < ntiles; ++tile) {
                const int tb = tile * TILE64;
                const bool have = (tile + 1 < ntiles);

                uint2 n0, n1, n2, n3;
                if (have) {
                    const int pb = startj + tb + TILE64 + q;
                    n0 = srt[pb];
                    n1 = srt[pb + 16];
                    n2 = srt[pb + 32];
                    n3 = srt[pb + 48];
                }

                // ---- 16 MFMA, 8 shared A-reads (2 col-blocks per read) ----
                f32x16 acc0, acc1;
                {
                    half8 av = *(const half8*)(const void*)&hb[arS];
                    acc0 = __builtin_amdgcn_mfma_f32_32x32x16_f16(av, bfrag0[0], zero16, 0, 0, 0);
                    acc1 = __builtin_amdgcn_mfma_f32_32x32x16_f16(av, bfrag1[0], zero16, 0, 0, 0);
                }
                #pragma unroll
                for (int kk = 1; kk < 8; ++kk) {
                    half8 av = *(const half8*)(const void*)&hb[arS + kk * 16];
                    acc0 = __builtin_amdgcn_mfma_f32_32x32x16_f16(av, bfrag0[kk], acc0, 0, 0, 0);
                    acc1 = __builtin_amdgcn_mfma_f32_32x32x16_f16(av, bfrag1[kk], acc1, 0, 0, 0);
                }

                // ---- stage next tile into hs (overlaps MFMA) ----
                if (have) {
                    STAGE_PT(n0, hs, st0);
                    STAGE_PT(n1, hs, st1);
                    STAGE_PT(n2, hs, st2);
                    STAGE_PT(n3, hs, st3);
                }

                // ---- running max over this group's 32 point-rows ----
                const int nv = n - tb - grp * 32;
                if (nv >= 32) {
                    #pragma unroll
                    for (int i = 0; i < 8; ++i) {
                        vmx0 = fmaxf(fmaxf(acc0[2 * i], acc0[2 * i + 1]), vmx0);
                        vmx1 = fmaxf(fmaxf(acc1[2 * i], acc1[2 * i + 1]), vmx1);
                    }
                } else {
                    #pragma unroll
                    for (int r = 0; r < 16; ++r) {
                        const int row = (r & 3) + 8 * (r >> 2) + 4 * khalf;
                        const bool v = row < nv;
                        vmx0 = fmaxf(vmx0, v ? acc0[r] : NEG_INF);
                        vmx1 = fmaxf(vmx1, v ? acc1[r] : NEG_INF);
                    }
                }
                __syncthreads();
                unsigned short* tmp = hb; hb = hs; hs = tmp;
            }
        }

        // ---- merge khalf, then cross-group via pool scratch, write ----
        vmx0 = fmaxf(vmx0, __shfl_xor(vmx0, 32, 64));
        vmx1 = fmaxf(vmx1, __shfl_xor(vmx1, 32, 64));
        float* red = (float*)pool;   // pool dead here (after loop-end barrier)
        if (lane < 32) {
            red[wave * 64 + col]      = vmx0;
            red[wave * 64 + 32 + col] = vmx1;
        }
        __syncthreads();
        if (wave < 2) {   // grp==0 waves: combine with partner grp==1 wave
            float v = fmaxf(red[wave * 64 + lane], red[(wave + 2) * 64 + lane]);
            out[(size_t)(nodebase + j) * H + wave * 64 + lane] =
                fmaxf(v + b2w, 0.f);   // relu + empty-node fill
        }
        __syncthreads();   // red consumed before next node overwrites pool
    }
    #undef STAGE_PT
}

// ---------------------------------------------------------------------------
// Tier B fallback: global-atomic counting sort + sorted node kernel (bf16)
// ---------------------------------------------------------------------------
__global__ void histB_kernel(const int* __restrict__ bidx, int* __restrict__ counts, int P) {
    int p = blockIdx.x * 256 + threadIdx.x;
    if (p < P) atomicAdd(&counts[bidx[p]], 1);
}
__global__ __launch_bounds__(1024)
void scanB_kernel(const int* __restrict__ counts, int* __restrict__ starts,
                  int* __restrict__ cursor, int N) {
    __shared__ int sums[1024];
    const int t = threadIdx.x;
    const int chunk = (N + 1023) >> 10;
    const int lo = t * chunk;
    const int hi = (lo + chunk < N) ? lo + chunk : N;
    int s = 0;
    for (int i = lo; i < hi; ++i) s += counts[i];
    sums[t] = s;
    __syncthreads();
    #pragma unroll
    for (int off = 1; off < 1024; off <<= 1) {
        int a = (t >= off) ? sums[t - off] : 0;
        __syncthreads();
        sums[t] += a;
        __syncthreads();
    }
    int run = sums[t] - s;
    for (int i = lo; i < hi; ++i) { starts[i] = run; cursor[i] = run; run += counts[i]; }
    if (t == 1023) starts[N] = sums[1023];
}
__global__ void scatterB_kernel(const int* __restrict__ bidx, const float* __restrict__ x,
                                int* __restrict__ cursor, uint2* __restrict__ xs, int P) {
    int p = blockIdx.x * 256 + threadIdx.x;
    if (p < P) {
        int pos = atomicAdd(&cursor[bidx[p]], 1);
        uint2 r;
        r.x = (unsigned)f2h(x[p * 3 + 0]) | ((unsigned)f2h(x[p * 3 + 1]) << 16);
        r.y = (unsigned)f2h(x[p * 3 + 2]);
        xs[pos] = r;
    }
}
__global__ void convw2_kernel(const float* __restrict__ W2, unsigned short* __restrict__ W2T) {
    int i = blockIdx.x * 256 + threadIdx.x;
    if (i < H * H) {
        int n = i >> 7, k = i & 127;
        W2T[i] = f2bf(W2[k * H + n]);
    }
}

__global__ __launch_bounds__(256, 4)
void node_kernelB(const uint2* __restrict__ xs,
                  const int*   __restrict__ starts,
                  const float* __restrict__ W1, const float* __restrict__ b1,
                  const float* __restrict__ gamma, const float* __restrict__ beta,
                  const float* __restrict__ rmean, const float* __restrict__ rvar,
                  const unsigned short* __restrict__ W2T, const float* __restrict__ b2,
                  float* __restrict__ out, int N)
{
    __shared__ __align__(16) unsigned short h1s[2][32 * ROW_STRIDE];
    const int t = threadIdx.x, lane = t & 63, wave = t >> 6;
    const int g = t & 15, q = t >> 4, c0 = g * 8;
    float2v w1f2[3][4], b1f2[4];
    #pragma unroll
    for (int jp = 0; jp < 4; ++jp)
        #pragma unroll
        for (int e = 0; e < 2; ++e) {
            int c = c0 + 2 * jp + e;
            float sc = gamma[c] * rsqrtf(rvar[c] + 1e-5f);
            w1f2[0][jp][e] = W1[0 * H + c] * sc;
            w1f2[1][jp][e] = W1[1 * H + c] * sc;
            w1f2[2][jp][e] = W1[2 * H + c] * sc;
            b1f2[jp][e]    = (b1[c] - rmean[c]) * sc + beta[c];
        }
    const int bn = lane & 15, kq = (lane >> 4) * 8;
    short8 bfrag[2][4]; float b2v[2];
    #pragma unroll
    for (int nt = 0; nt < 2; ++nt) {
        const int nn = wave * 32 + nt * 16 + bn;
        b2v[nt] = b2[nn];
        #pragma unroll
        for (int kk = 0; kk < 4; ++kk)
            bfrag[nt][kk] = *(const short8*)&W2T[nn * H + kk * 32 + kq];
    }
    const float4v zero4 = {0.f, 0.f, 0.f, 0.f};
    const float NEG_INF = -__builtin_inff();
    const float2v zero2 = {0.f, 0.f};
    for (int node = blockIdx.x; node < N; node += gridDim.x) {
        const int start = starts[node];
        const int n = starts[node + 1] - start;
        const int ntiles = (n + 31) >> 5;
        float2v vmax2[2];
        vmax2[0] = float2v{NEG_INF, NEG_INF};
        vmax2[1] = float2v{NEG_INF, NEG_INF};
        auto loadx = [&](int tb, float xv[2][3]) {
            #pragma unroll
            for (int i = 0; i < 2; ++i) {
                uint2 r = xs[start + tb + q + 16 * i];
                xv[i][0] = h2f((unsigned short)(r.x & 0xffffu));
                xv[i][1] = h2f((unsigned short)(r.x >> 16));
                xv[i][2] = h2f((unsigned short)(r.y & 0xffffu));
            }
        };
        auto stage = [&](const float xv[2][3], unsigned short* buf) {
            #pragma unroll
            for (int i = 0; i < 2; ++i) {
                const int pl = q + 16 * i;
                float2v a0 = {xv[i][0], xv[i][0]};
                float2v a1 = {xv[i][1], xv[i][1]};
                float2v a2 = {xv[i][2], xv[i][2]};
                int4v pk;
                #pragma unroll
                for (int jp = 0; jp < 4; ++jp) {
                    float2v h = b1f2[jp];
                    h = __builtin_elementwise_fma(a0, w1f2[0][jp], h);
                    h = __builtin_elementwise_fma(a1, w1f2[1][jp], h);
                    h = __builtin_elementwise_fma(a2, w1f2[2][jp], h);
                    h = __builtin_elementwise_max(h, zero2);
                    pk[jp] = (int)pkbf(h[0], h[1]);
                }
                *(int4v*)(void*)&buf[pl * ROW_STRIDE + c0] = pk;
            }
        };
        if (ntiles > 0) {
            float xv[2][3];
            loadx(0, xv);
            stage(xv, h1s[0]);
            __syncthreads();
            int pb = 0;
            for (int tile = 0; tile < ntiles; ++tile) {
                const int tb = tile * 32;
                const bool havenext = (tile + 1 < ntiles);
                float nx[2][3];
                if (havenext) loadx(tb + 32, nx);
                float4v acc[2][2];
                const unsigned short* hb = h1s[pb];
                {
                    short8 a0 = *(const short8*)&hb[bn * ROW_STRIDE + kq];
                    short8 a1 = *(const short8*)&hb[(16 + bn) * ROW_STRIDE + kq];
                    #pragma unroll
                    for (int nt = 0; nt < 2; ++nt) {
                        acc[0][nt] = __builtin_amdgcn_mfma_f32_16x16x32_bf16(a0, bfrag[nt][0], zero4, 0, 0, 0);
                        acc[1][nt] = __builtin_amdgcn_mfma_f32_16x16x32_bf16(a1, bfrag[nt][0], zero4, 0, 0, 0);
                    }
                }
                #pragma unroll
                for (int kk = 1; kk < 4; ++kk) {
                    short8 a0 = *(const short8*)&hb[bn * ROW_STRIDE + kk * 32 + kq];
                    short8 a1 = *(const short8*)&hb[(16 + bn) * ROW_STRIDE + kk * 32 + kq];
                    #pragma unroll
                    for (int nt = 0; nt < 2; ++nt) {
                        acc[0][nt] = __builtin_amdgcn_mfma_f32_16x16x32_bf16(a0, bfrag[nt][kk], acc[0][nt], 0, 0, 0);
                        acc[1][nt] = __builtin_amdgcn_mfma_f32_16x16x32_bf16(a1, bfrag[nt][kk], acc[1][nt], 0, 0, 0);
                    }
                }
                if (havenext) stage(nx, h1s[pb ^ 1]);
                if (tb + 32 <= n) {
                    #pragma unroll
                    for (int ps = 0; ps < 2; ++ps)
                        #pragma unroll
                        for (int nt = 0; nt < 2; ++nt) {
                            vmax2[nt] = __builtin_elementwise_max(vmax2[nt],
                                          float2v{acc[ps][nt][0], acc[ps][nt][1]});
                            vmax2[nt] = __builtin_elementwise_max(vmax2[nt],
                                          float2v{acc[ps][nt][2], acc[ps][nt][3]});
                        }
                } else {
                    #pragma unroll
                    for (int ps = 0; ps < 2; ++ps)
                        #pragma unroll
                        for (int r = 0; r < 4; ++r) {
                            const int pl = ps * 16 + (lane >> 4) * 4 + r;
                            const bool valid = (tb + pl) < n;
                            vmax2[0][r & 1] = fmaxf(vmax2[0][r & 1], valid ? acc[ps][0][r] : NEG_INF);
                            vmax2[1][r & 1] = fmaxf(vmax2[1][r & 1], valid ? acc[ps][1][r] : NEG_INF);
                        }
                }
                __syncthreads();
                pb ^= 1;
            }
        }
        float vmax0 = fmaxf(vmax2[0][0], vmax2[0][1]);
        float vmax1 = fmaxf(vmax2[1][0], vmax2[1][1]);
        vmax0 = fmaxf(vmax0, __shfl_xor(vmax0, 16, 64));
        vmax0 = fmaxf(vmax0, __shfl_xor(vmax0, 32, 64));
        vmax1 = fmaxf(vmax1, __shfl_xor(vmax1, 16, 64));
        vmax1 = fmaxf(vmax1, __shfl_xor(vmax1, 32, 64));
        if (lane < 16) {
            float* orow = out + (size_t)node * H + wave * 32;
            orow[lane]      = fmaxf(vmax0 + b2v[0], 0.f);
            orow[16 + lane] = fmaxf(vmax1 + b2v[1], 0.f);
        }
    }
}

extern "C" void kernel_launch(void* const* d_in, const int* in_sizes, int n_in,
                              void* d_out, int out_size, void* d_ws, size_t ws_size,
                              hipStream_t stream) {
    const float* x     = (const float*)d_in[0];
    const int*   bidx  = (const int*)  d_in[1];
    const float* W1    = (const float*)d_in[3];
    const float* b1    = (const float*)d_in[4];
    const float* gamma = (const float*)d_in[5];
    const float* beta  = (const float*)d_in[6];
    const float* rmean = (const float*)d_in[7];
    const float* rvar  = (const float*)d_in[8];
    const float* W2    = (const float*)d_in[9];
    const float* b2    = (const float*)d_in[10];
    float* out = (float*)d_out;

    const int P = in_sizes[1];
    const int N = out_size / H;
    const int nbuk = (N + NPB - 1) >> BSH;
    const size_t szW2T = 32768;
    const size_t lds1  = (size_t)4 * nbuk;
    char* w = (char*)d_ws;

    if (lds1 <= 60000) {
        // Tier A, 8-way XCD-partitioned xb (write-coalescing in per-XCD L2)
        {
            const int npa = 8, cpa = 320;
            const size_t szG  = (size_t)4 * (((size_t)nbuk * npa + 63) & ~(size_t)63);
            const size_t szXb = (size_t)8 * ((size_t)cpa * npa * nbuk + 64);
            const size_t need = szW2T + szG + szXb + 256;
            if (ws_size >= need) {
                unsigned short* W2T = (unsigned short*)w;
                int* gcnt = (int*)(w + szW2T);
                uint2* xb = (uint2*)(w + szW2T + szG);
                hipMemsetAsync(gcnt, 0, (size_t)nbuk * npa * sizeof(int), stream);
                scatter_slot<<<NBLK, BT, lds1, stream>>>(bidx, x, W2, W2T, gcnt, xb,
                                                         P, nbuk, npa, cpa);
                node_kernel16<<<nbuk, 256, 0, stream>>>(xb, gcnt, W1, b1, gamma, beta,
                                                        rmean, rvar, W2T, b2, out, N,
                                                        npa, cpa);
                return;
            }
        }
        // Tier A, legacy single-partition layout
        {
            const int npa = 1, cpa = CAP;
            const size_t szG  = (size_t)4 * (((size_t)nbuk + 63) & ~(size_t)63);
            const size_t szXb = (size_t)8 * ((size_t)cpa * nbuk + 64);
            const size_t need = szW2T + szG + szXb + 256;
            if (ws_size >= need) {
                unsigned short* W2T = (unsigned short*)w;
                int* gcnt = (int*)(w + szW2T);
                uint2* xb = (uint2*)(w + szW2T + szG);
                hipMemsetAsync(gcnt, 0, (size_t)nbuk * sizeof(int), stream);
                scatter_slot<<<NBLK, BT, lds1, stream>>>(bidx, x, W2, W2T, gcnt, xb,
                                                         P, nbuk, npa, cpa);
                node_kernel16<<<nbuk, 256, 0, stream>>>(xb, gcnt, W1, b1, gamma, beta,
                                                        rmean, rvar, W2T, b2, out, N,
                                                        npa, cpa);
                return;
            }
        }
    }

    // Tier B: global-atomic counting sort
    const int Npad = (N + 63) & ~63;
    const size_t szStarts = (size_t)4 * (Npad + 64);
    const size_t szCnt    = (size_t)4 * Npad;
    const size_t szRec    = (size_t)8 * (P + 64);
    const size_t needB    = szStarts + szW2T + 2 * szCnt + szRec + 256;
    if (ws_size >= needB) {
        int* starts = (int*)w;
        unsigned short* W2T = (unsigned short*)(w + szStarts);
        int* counts = (int*)(w + szStarts + szW2T);
        int* cursor = (int*)(w + szStarts + szW2T + szCnt);
        uint2* xs   = (uint2*)(w + szStarts + szW2T + 2 * szCnt);

        hipMemsetAsync(counts, 0, (size_t)N * sizeof(int), stream);
        const int pblocks = (P + 255) / 256;
        const int grid = (N < 2048) ? N : 2048;
        convw2_kernel<<<(H * H + 255) / 256, 256, 0, stream>>>(W2, W2T);
        histB_kernel<<<pblocks, 256, 0, stream>>>(bidx, counts, P);
        scanB_kernel<<<1, 1024, 0, stream>>>(counts, starts, cursor, N);
        scatterB_kernel<<<pblocks, 256, 0, stream>>>(bidx, x, cursor, xs, P);
        node_kernelB<<<grid, 256, 0, stream>>>(xs, starts, W1, b1, gamma, beta,
                                               rmean, rvar, W2T, b2, out, N);
    }
}